// Round 1
// baseline (120.081 us; speedup 1.0000x reference)
//
#include <hip/hip_runtime.h>
#include <hip/hip_bf16.h>

typedef short s8v __attribute__((ext_vector_type(8)));   // 8 bf16 (4 VGPRs) MFMA A/B frag
typedef float f4v __attribute__((ext_vector_type(4)));   // MFMA C/D frag

__device__ __forceinline__ unsigned short f2bf(float x) {  // RTNE fp32->bf16
  unsigned u = __builtin_bit_cast(unsigned, x);
  u += 0x7fffu + ((u >> 16) & 1u);
  return (unsigned short)(u >> 16);
}

constexpr int NLAT = 8192;
constexpr int HID  = 128;
constexpr int MWG  = 128;   // rows per workgroup (= 64 queries x 2 passes)

// ---------- prep: pack W1/W2 as bf16 B-fragments (lane-contiguous 16B) into ws ----------
// W1f: 8192 elems  (K=64: k'<13 -> W1 row k'; 13..15 -> 0 pad; 16..63 -> W1 row k'-3)
// W2f: 16384 elems (K=128)
__global__ void prep_kernel(const float* __restrict__ W1, const float* __restrict__ W2,
                            unsigned short* __restrict__ wsW) {
  int e = blockIdx.x * 256 + threadIdx.x;   // 96 blocks * 256 = 24576 exactly
  if (e < 8192) {
    int frag = e >> 9, rem = e & 511, lane = rem >> 3, j = rem & 7;
    int nt = frag >> 1, ks = frag & 1;
    int k = ks * 32 + (lane >> 4) * 8 + j;   // reordered input dim
    int n = nt * 16 + (lane & 15);
    float v = 0.0f;
    if (k < 13) v = W1[k * HID + n];
    else if (k >= 16) v = W1[(k - 3) * HID + n];
    wsW[e] = f2bf(v);
  } else {
    int e2 = e - 8192;
    int frag = e2 >> 9, rem = e2 & 511, lane = rem >> 3, j = rem & 7;
    int nt = frag >> 2, ks = frag & 3;
    int k = ks * 32 + (lane >> 4) * 8 + j;
    int n = nt * 16 + (lane & 15);
    wsW[8192 + e2] = f2bf(W2[k * HID + n]);
  }
}

// ---------- main fused kernel ----------
__global__ __launch_bounds__(256, 3) void lisagon_main(
    const float* __restrict__ coord, const float* __restrict__ latent,
    const unsigned short* __restrict__ W1f, const unsigned short* __restrict__ W2f,
    const float* __restrict__ b1, const float* __restrict__ b2,
    const float* __restrict__ W3, const float* __restrict__ b3,
    float* __restrict__ out) {
  // XOR-swizzled tiles: 16B chunk c of row r stored at position c ^ (r & (nchunk-1))
  __shared__ __align__(16) unsigned short A1[MWG * 64];    // 16 KB  (input, K=64)
  __shared__ __align__(16) unsigned short H1[MWG * 128];   // 32 KB  (hidden1)
  __shared__ float AREA[MWG];

  const int t = threadIdx.x;
  const int lane = t & 63, wv = t >> 6;
  const int l15 = lane & 15, q4 = lane >> 4;

  // per-lane broadcast constants (column j = nt*16 + l15)
  float b1v[8], b2v[8], w3v[8];
#pragma unroll
  for (int nt = 0; nt < 8; nt++) {
    b1v[nt] = b1[nt * 16 + l15];
    b2v[nt] = b2[nt * 16 + l15];
    w3v[nt] = W3[nt * 16 + l15];
  }
  const float b3s = b3[0];

  // ---- phase 0: build swizzled bf16 input tile ----
  {
    const int r = t & 127, sec = t >> 7;        // 2 threads per row
    const int Rg = blockIdx.x * MWG + r;        // global row = query*2 + pass
    const int gq = Rg >> 1, p = Rg & 1;         // p=0 -> vx=-2, p=1 -> vx=0
    const float co = coord[gq];
    const float vxrx = p ? 0.0f : -0.000244140625f;   // vx * rx, exact
    float c = (co + vxrx) + 1e-6f;
    const float lo = -1.0f + 1e-6f, hi = 1.0f - 1e-6f;
    c = fminf(fmaxf(c, lo), hi);
    // exact searchsorted on the uniform grid: grid[n] = ((2n+1)-N)/N exactly in fp32
    double u = ((double)c * 8192.0 + 8191.0) * 0.5;
    int idx = (int)ceil(u);
    idx = min(max(idx, 0), NLAT - 1);

    uint4* A1v = (uint4*)A1;
    if (sec == 0) {
      float qc = ((float)(2 * idx + 1) - 8192.0f) * (1.0f / 8192.0f);  // exact grid[idx]
      float rel = (co - qc) * 8192.0f;
      AREA[r] = fabsf(rel) + 1e-9f;
      float v[16];
      v[0] = rel;
      float f = rel;
#pragma unroll
      for (int i = 0; i < 6; i++) {
        v[1 + 2 * i] = __sinf(f);
        v[2 + 2 * i] = __cosf(f);
        f = f + f;                 // exact power-of-2 freqs
      }
      v[13] = v[14] = v[15] = 0.0f;
#pragma unroll
      for (int ch = 0; ch < 2; ch++) {
        union { uint4 u4; unsigned short us[8]; } pk;
#pragma unroll
        for (int j = 0; j < 8; j++) pk.us[j] = f2bf(v[ch * 8 + j]);
        A1v[r * 8 + (ch ^ (r & 7))] = pk.u4;
      }
    } else {
      const float4* latv = (const float4*)(latent + (size_t)(gq >> 16) * (NLAT * 16));
      int rows3[3];
      rows3[0] = max(idx - 1, 0);
      rows3[1] = idx;
      rows3[2] = min(idx + 1, NLAT - 1);
#pragma unroll
      for (int s = 0; s < 3; s++) {
        float4 a = latv[rows3[s] * 4 + 0];
        float4 b = latv[rows3[s] * 4 + 1];
        float4 cc = latv[rows3[s] * 4 + 2];
        float4 d = latv[rows3[s] * 4 + 3];
        union { uint4 u4; unsigned short us[8]; } p0, p1;
        p0.us[0] = f2bf(a.x); p0.us[1] = f2bf(a.y); p0.us[2] = f2bf(a.z); p0.us[3] = f2bf(a.w);
        p0.us[4] = f2bf(b.x); p0.us[5] = f2bf(b.y); p0.us[6] = f2bf(b.z); p0.us[7] = f2bf(b.w);
        p1.us[0] = f2bf(cc.x); p1.us[1] = f2bf(cc.y); p1.us[2] = f2bf(cc.z); p1.us[3] = f2bf(cc.w);
        p1.us[4] = f2bf(d.x); p1.us[5] = f2bf(d.y); p1.us[6] = f2bf(d.z); p1.us[7] = f2bf(d.w);
        int ch0 = 2 + 2 * s;
        A1v[r * 8 + (ch0 ^ (r & 7))]       = p0.u4;
        A1v[r * 8 + ((ch0 + 1) ^ (r & 7))] = p1.u4;
      }
    }
  }
  __syncthreads();

  const int wbase = wv * 32;     // each wave owns 32 rows x 128 cols
  const s8v* W1fv = (const s8v*)W1f;
  const s8v* W2fv = (const s8v*)W2f;

  // ---- GEMM1: [32x64] @ [64x128] ----
  f4v acc[2][8];
#pragma unroll
  for (int mt = 0; mt < 2; mt++)
#pragma unroll
    for (int nt = 0; nt < 8; nt++) acc[mt][nt] = (f4v){0.f, 0.f, 0.f, 0.f};

#pragma unroll
  for (int ks = 0; ks < 2; ks++) {
    s8v Bf[8];
#pragma unroll
    for (int nt = 0; nt < 8; nt++) Bf[nt] = W1fv[(nt * 2 + ks) * 64 + lane];
    s8v Af[2];
#pragma unroll
    for (int mt = 0; mt < 2; mt++) {
      int row = wbase + mt * 16 + l15;
      Af[mt] = ((const s8v*)A1)[row * 8 + ((ks * 4 + q4) ^ (row & 7))];
    }
#pragma unroll
    for (int mt = 0; mt < 2; mt++)
#pragma unroll
      for (int nt = 0; nt < 8; nt++)
        acc[mt][nt] = __builtin_amdgcn_mfma_f32_16x16x32_bf16(Af[mt], Bf[nt], acc[mt][nt], 0, 0, 0);
  }

  // bias + relu -> swizzled H1 (C-layout: col = l15+16nt, row = q4*4+i)
#pragma unroll
  for (int mt = 0; mt < 2; mt++)
#pragma unroll
    for (int nt = 0; nt < 8; nt++)
#pragma unroll
      for (int i = 0; i < 4; i++) {
        float hv = fmaxf(acc[mt][nt][i] + b1v[nt], 0.0f);
        int row = wbase + mt * 16 + q4 * 4 + i;
        int col = nt * 16 + l15;
        H1[row * 128 + (((col >> 3) ^ (row & 15)) * 8) + (col & 7)] = f2bf(hv);
      }
  __syncthreads();

  // ---- GEMM2: [32x128] @ [128x128] ----
  f4v acc2[2][8];
#pragma unroll
  for (int mt = 0; mt < 2; mt++)
#pragma unroll
    for (int nt = 0; nt < 8; nt++) acc2[mt][nt] = (f4v){0.f, 0.f, 0.f, 0.f};

#pragma unroll
  for (int ks = 0; ks < 4; ks++) {
    s8v Bf[8];
#pragma unroll
    for (int nt = 0; nt < 8; nt++) Bf[nt] = W2fv[(nt * 4 + ks) * 64 + lane];
    s8v Af[2];
#pragma unroll
    for (int mt = 0; mt < 2; mt++) {
      int row = wbase + mt * 16 + l15;
      Af[mt] = ((const s8v*)H1)[row * 16 + ((ks * 4 + q4) ^ (row & 15))];
    }
#pragma unroll
    for (int mt = 0; mt < 2; mt++)
#pragma unroll
      for (int nt = 0; nt < 8; nt++)
        acc2[mt][nt] = __builtin_amdgcn_mfma_f32_16x16x32_bf16(Af[mt], Bf[nt], acc2[mt][nt], 0, 0, 0);
  }

  // ---- layer 3 (dot with w3) + pass-combine ----
  float pr[8];
#pragma unroll
  for (int mt = 0; mt < 2; mt++)
#pragma unroll
    for (int i = 0; i < 4; i++) {
      float s = 0.f;
#pragma unroll
      for (int nt = 0; nt < 8; nt++)
        s += fmaxf(acc2[mt][nt][i] + b2v[nt], 0.f) * w3v[nt];
      pr[mt * 4 + i] = s;
    }
#pragma unroll
  for (int m = 1; m < 16; m <<= 1)
#pragma unroll
    for (int k = 0; k < 8; k++) pr[k] += __shfl_xor(pr[k], m, 64);

  if (l15 == 0) {
#pragma unroll
    for (int mt = 0; mt < 2; mt++)
#pragma unroll
      for (int u = 0; u < 2; u++) {
        int row0 = wbase + mt * 16 + q4 * 4 + 2 * u;    // even local row = pass0
        float p0 = pr[mt * 4 + 2 * u] + b3s;
        float p1 = pr[mt * 4 + 2 * u + 1] + b3s;
        float a0 = AREA[row0], a1 = AREA[row0 + 1];
        float tot = a0 + a1;
        out[(blockIdx.x * MWG + row0) >> 1] = p0 * (a1 / tot) + p1 * (a0 / tot);
      }
  }
}

extern "C" void kernel_launch(void* const* d_in, const int* in_sizes, int n_in,
                              void* d_out, int out_size, void* d_ws, size_t ws_size,
                              hipStream_t stream) {
  const float* coord  = (const float*)d_in[0];
  const float* latent = (const float*)d_in[1];
  const float* W1 = (const float*)d_in[2];
  const float* b1 = (const float*)d_in[3];
  const float* W2 = (const float*)d_in[4];
  const float* b2 = (const float*)d_in[5];
  const float* W3 = (const float*)d_in[6];
  const float* b3 = (const float*)d_in[7];
  float* out = (float*)d_out;
  unsigned short* wsW = (unsigned short*)d_ws;   // [0,8192) W1f, [8192,24576) W2f

  prep_kernel<<<96, 256, 0, stream>>>(W1, W2, wsW);
  lisagon_main<<<4096, 256, 0, stream>>>(coord, latent, wsW, wsW + 8192,
                                         b1, b2, W3, b3, out);
}